// Round 4
// baseline (114.426 us; speedup 1.0000x reference)
//
#include <hip/hip_runtime.h>
#include <hip/hip_fp16.h>
#include <math.h>

#define NEARP 0.01f
#define BLUR 0.3f
#define MAX_ALPHA 0.999f
#define TILE 16
#define NSEG 16
#define QCUT 32.0f   // quad cutoff: culled alpha <= op*e^-16 ~ 3e-8 each

__device__ __forceinline__ float sigmoidf_(float x) {
    return 1.0f / (1.0f + expf(-x));
}

// ---------------------------------------------------------------------------
// Stage 1: preprocess -> bbox float4 (m2x,m2y,r,-) + payload 2x float4 + tz
// payload: f0=(m2x, m2y, ia', ib'')  f1=(ic', op, rg_half2, b)
// conic pre-scaled: quad' = ia'dx^2 + ib''dxdy + ic'dy^2 ; alpha = op*exp2(quad')
// ---------------------------------------------------------------------------
__global__ void gs_preprocess(const float* __restrict__ viewmats,
                              const float* __restrict__ Ks,
                              const float* __restrict__ means,
                              const float* __restrict__ quats,
                              const float* __restrict__ log_scales,
                              const float* __restrict__ opac_logits,
                              const float* __restrict__ color_logits,
                              float4* __restrict__ ubbox,
                              float4* __restrict__ upay,
                              float* __restrict__ tz_out,
                              int N, int C) {
    int idx = blockIdx.x * blockDim.x + threadIdx.x;
    if (idx >= N * C) return;
    int c = idx / N;
    int n = idx - c * N;

    float qw = quats[n * 4 + 0], qx = quats[n * 4 + 1];
    float qy = quats[n * 4 + 2], qz = quats[n * 4 + 3];
    float qn = rsqrtf(qw * qw + qx * qx + qy * qy + qz * qz);
    float w = qw * qn, x = qx * qn, y = qy * qn, z = qz * qn;
    float R00 = 1.0f - 2.0f * (y * y + z * z), R01 = 2.0f * (x * y - w * z), R02 = 2.0f * (x * z + w * y);
    float R10 = 2.0f * (x * y + w * z), R11 = 1.0f - 2.0f * (x * x + z * z), R12 = 2.0f * (y * z - w * x);
    float R20 = 2.0f * (x * z - w * y), R21 = 2.0f * (y * z + w * x), R22 = 1.0f - 2.0f * (x * x + y * y);

    float s0 = expf(log_scales[n * 3 + 0]);
    float s1 = expf(log_scales[n * 3 + 1]);
    float s2 = expf(log_scales[n * 3 + 2]);

    float M00 = R00 * s0, M01 = R01 * s1, M02 = R02 * s2;
    float M10 = R10 * s0, M11 = R11 * s1, M12 = R12 * s2;
    float M20 = R20 * s0, M21 = R21 * s1, M22 = R22 * s2;
    float C00 = M00 * M00 + M01 * M01 + M02 * M02;
    float C01 = M00 * M10 + M01 * M11 + M02 * M12;
    float C02 = M00 * M20 + M01 * M21 + M02 * M22;
    float C11 = M10 * M10 + M11 * M11 + M12 * M12;
    float C12 = M10 * M20 + M11 * M21 + M12 * M22;
    float C22 = M20 * M20 + M21 * M21 + M22 * M22;

    const float* vm = viewmats + c * 16;
    float V00 = vm[0], V01 = vm[1], V02 = vm[2], T0 = vm[3];
    float V10 = vm[4], V11 = vm[5], V12 = vm[6], T1 = vm[7];
    float V20 = vm[8], V21 = vm[9], V22 = vm[10], T2 = vm[11];
    float mex = means[n * 3 + 0], mey = means[n * 3 + 1], mez = means[n * 3 + 2];
    float tx = V00 * mex + V01 * mey + V02 * mez + T0;
    float ty = V10 * mex + V11 * mey + V12 * mez + T1;
    float tz = V20 * mex + V21 * mey + V22 * mez + T2;

    float fx = Ks[c * 9 + 0], fy = Ks[c * 9 + 4], cx = Ks[c * 9 + 2], cy = Ks[c * 9 + 5];
    float tzs = (tz > NEARP) ? tz : NEARP;
    float iz = 1.0f / tzs;
    float m2x = fx * tx * iz + cx;
    float m2y = fy * ty * iz + cy;

    float A00 = V00 * C00 + V01 * C01 + V02 * C02;
    float A01 = V00 * C01 + V01 * C11 + V02 * C12;
    float A02 = V00 * C02 + V01 * C12 + V02 * C22;
    float A10 = V10 * C00 + V11 * C01 + V12 * C02;
    float A11 = V10 * C01 + V11 * C11 + V12 * C12;
    float A12 = V10 * C02 + V11 * C12 + V12 * C22;
    float A20 = V20 * C00 + V21 * C01 + V22 * C02;
    float A21 = V20 * C01 + V21 * C11 + V22 * C12;
    float A22 = V20 * C02 + V21 * C12 + V22 * C22;
    float S00 = A00 * V00 + A01 * V01 + A02 * V02;
    float S01 = A00 * V10 + A01 * V11 + A02 * V12;
    float S02 = A00 * V20 + A01 * V21 + A02 * V22;
    float S11 = A10 * V10 + A11 * V11 + A12 * V12;
    float S12 = A10 * V20 + A11 * V21 + A12 * V22;
    float S22 = A20 * V20 + A21 * V21 + A22 * V22;

    float J00 = fx * iz, J02 = -fx * tx * iz * iz;
    float J11 = fy * iz, J12 = -fy * ty * iz * iz;

    float c2_00 = J00 * J00 * S00 + 2.0f * J00 * J02 * S02 + J02 * J02 * S22;
    float c2_01 = J00 * J11 * S01 + J00 * J12 * S02 + J02 * J11 * S12 + J02 * J12 * S22;
    float c2_11 = J11 * J11 * S11 + 2.0f * J11 * J12 * S12 + J12 * J12 * S22;

    float a = c2_00 + BLUR;
    float cc = c2_11 + BLUR;
    float b = c2_01;
    float det = a * cc - b * b;
    bool valid = (tz > NEARP) && (det > 1e-12f);

    float ia, ib, ic, op, r;
    if (valid) {
        float inv = 1.0f / det;
        ia = cc * inv;
        ib = -b * inv;
        ic = a * inv;
        op = sigmoidf_(opac_logits[n]);
        float lmax = 0.5f * (a + cc) + sqrtf(0.25f * (a - cc) * (a - cc) + b * b);
        r = sqrtf(QCUT * lmax);
    } else {
        ia = 0.0f; ib = 0.0f; ic = 0.0f; op = 0.0f;
        r = -1.0f;  // culled from every tile; contribution is exactly 0 anyway
    }
    float cr = sigmoidf_(color_logits[n * 3 + 0]);
    float cg = sigmoidf_(color_logits[n * 3 + 1]);
    float cb = sigmoidf_(color_logits[n * 3 + 2]);

    // fold -0.5*log2(e) into conic so alpha = op * exp2(quad')
    const float KQ = 0.721347520444482f;   // 0.5*log2(e)
    float iap = -KQ * ia;
    float ibp = -2.0f * KQ * ib;
    float icp = -KQ * ic;

    union { __half2 h; float f; } pk;
    pk.h = __floats2half2_rn(cr, cg);

    int gi = c * N + n;
    ubbox[gi] = make_float4(m2x, m2y, r, 0.0f);
    upay[(size_t)gi * 2 + 0] = make_float4(m2x, m2y, iap, ibp);
    upay[(size_t)gi * 2 + 1] = make_float4(icp, op, pk.f, cb);
    tz_out[gi] = tz;
}

// ---------------------------------------------------------------------------
// Stage 2: wave-per-element stable rank sort; scatter bbox + payload to rank.
// ---------------------------------------------------------------------------
__global__ void gs_sort_wave(const float4* __restrict__ ubbox,
                             const float4* __restrict__ upay,
                             const float* __restrict__ tzin,
                             float4* __restrict__ sbbox,
                             float4* __restrict__ spay,
                             int N, int C) {
    int gtid = blockIdx.x * blockDim.x + threadIdx.x;
    int wid = gtid >> 6;
    int lane = gtid & 63;
    if (wid >= C * N) return;
    int c = wid / N;
    int i = wid - c * N;
    const float* tzc = tzin + (size_t)c * N;
    float ti = tzc[i];
    int rank = 0;
    for (int j = lane; j < N; j += 64) {
        float tj = tzc[j];
        rank += (int)((tj < ti) || (tj == ti && j < i));  // stable
    }
#pragma unroll
    for (int off = 1; off < 64; off <<= 1)
        rank += __shfl_xor(rank, off, 64);
    int src = c * N + i;
    int dst = c * N + rank;
    if (lane == 0) sbbox[dst] = ubbox[src];
    if (lane < 2) spay[(size_t)dst * 2 + lane] = upay[(size_t)src * 2 + lane];
}

// ---------------------------------------------------------------------------
// Stage 3: per-(cam,tile) order-preserving compaction of overlapping gaussians.
// One wave per tile; ballot-compact sorted indices whose bbox hits the tile.
// ---------------------------------------------------------------------------
__global__ void gs_tilebuild(const float4* __restrict__ sbbox,
                             int* __restrict__ tcount,
                             int* __restrict__ tlist,
                             int N, int C, int tilesx, int tilesy) {
    int gtid = blockIdx.x * blockDim.x + threadIdx.x;
    int wid = gtid >> 6;
    int lane = gtid & 63;
    int T = tilesx * tilesy;
    if (wid >= C * T) return;
    int c = wid / T;
    int t = wid - c * T;
    float x0 = (float)((t % tilesx) * TILE);
    float y0 = (float)((t / tilesx) * TILE);
    float x1 = x0 + (float)TILE;
    float y1 = y0 + (float)TILE;

    const float4* bb = sbbox + (size_t)c * N;
    int* lst = tlist + (size_t)wid * N;
    int cnt = 0;
    for (int base = 0; base < N; base += 64) {
        int g = base + lane;
        bool pred = false;
        if (g < N) {
            float4 b = bb[g];
            pred = (b.z >= 0.0f) &&
                   (b.x - b.z <= x1) && (b.x + b.z >= x0) &&
                   (b.y - b.z <= y1) && (b.y + b.z >= y0);
        }
        unsigned long long bal = __ballot(pred);
        if (pred) {
            int off = __popcll(bal & ((1ull << lane) - 1ull));
            lst[cnt + off] = g;
        }
        cnt += (int)__popcll(bal);
    }
    if (lane == 0) tcount[wid] = cnt;
}

// ---------------------------------------------------------------------------
// Stage 4: render — each block = (tile, segment slice of that tile's list).
// Uniform L1-hit loads per gaussian; no LDS, no syncthreads.
// ---------------------------------------------------------------------------
__global__ void __launch_bounds__(256) gs_render_tile(const float4* __restrict__ spay,
                                                      const int* __restrict__ tcount,
                                                      const int* __restrict__ tlist,
                                                      float4* __restrict__ partial,
                                                      int N, int W, int H,
                                                      int tilesx, int nseg) {
    int zc = blockIdx.z;                  // zc = c*nseg + s
    int c = zc / nseg;
    int s = zc - c * nseg;
    int t = blockIdx.y * tilesx + blockIdx.x;
    int T = tilesx * ((H + TILE - 1) / TILE);
    int wid = c * T + t;

    int cnt = tcount[wid];
    int L = (cnt + nseg - 1) / nseg;
    int k0 = s * L;
    int k1 = min(cnt, k0 + L);

    int lx = threadIdx.x % TILE;
    int ly = threadIdx.x / TILE;
    int x = blockIdx.x * TILE + lx;
    int y = blockIdx.y * TILE + ly;
    float px = (float)x + 0.5f;
    float py = (float)y + 0.5f;

    float Tr = 1.0f, accr = 0.0f, accg = 0.0f, accb = 0.0f;
    const int* lst = tlist + (size_t)wid * N;
    const float4* pay = spay + (size_t)c * N * 2;

#pragma unroll 4
    for (int k = k0; k < k1; k++) {
        int idx = lst[k];                           // wave-uniform
        float4 f0 = pay[(size_t)idx * 2 + 0];
        float4 f1 = pay[(size_t)idx * 2 + 1];
        float dx = px - f0.x;
        float dy = py - f0.y;
        float quad = dx * (f0.z * dx + f0.w * dy) + f1.x * dy * dy;  // <= 0
        float alpha = f1.y * exp2f(quad);
        alpha = fminf(alpha, MAX_ALPHA);
        union { float f; __half2 h; } pk; pk.f = f1.z;
        float wgt = alpha * Tr;
        accr += wgt * __low2float(pk.h);
        accg += wgt * __high2float(pk.h);
        accb += wgt * f1.w;
        Tr *= (1.0f - alpha);
    }
    if (x < W && y < H) {
        partial[((size_t)zc * H + y) * W + x] = make_float4(accr, accg, accb, Tr);
    }
}

// ---------------------------------------------------------------------------
// Stage 5: fold nseg partials per pixel, in segment order.
// ---------------------------------------------------------------------------
__global__ void gs_combine(const float4* __restrict__ partial,
                           float* __restrict__ out,
                           int W, int H, int nseg, int C) {
    int pid = blockIdx.x * blockDim.x + threadIdx.x;
    int PIX = W * H;
    if (pid >= C * PIX) return;
    int c = pid / PIX;
    int p = pid - c * PIX;
    float T = 1.0f, r = 0.0f, g = 0.0f, b = 0.0f;
    for (int s = 0; s < nseg; s++) {
        float4 ps = partial[(size_t)(c * nseg + s) * PIX + p];
        r += T * ps.x;
        g += T * ps.y;
        b += T * ps.z;
        T *= ps.w;
    }
    size_t o = (size_t)pid * 3;
    out[o + 0] = r;
    out[o + 1] = g;
    out[o + 2] = b;
}

extern "C" void kernel_launch(void* const* d_in, const int* in_sizes, int n_in,
                              void* d_out, int out_size, void* d_ws, size_t ws_size,
                              hipStream_t stream) {
    const float* viewmats = (const float*)d_in[0];
    const float* Ks = (const float*)d_in[1];
    const float* means = (const float*)d_in[2];
    const float* quats = (const float*)d_in[3];
    const float* log_scales = (const float*)d_in[4];
    const float* opac_logits = (const float*)d_in[5];
    const float* color_logits = (const float*)d_in[6];
    float* out = (float*)d_out;

    int N = in_sizes[2] / 3;       // means: (N,3)
    int C = in_sizes[0] / 16;      // viewmats: (C,4,4)
    int pix = out_size / (C * 3);
    int W = (int)(sqrt((double)pix) + 0.5);
    int H = pix / W;
    int tilesx = (W + TILE - 1) / TILE;
    int tilesy = (H + TILE - 1) / TILE;
    int T = tilesx * tilesy;
    int nseg = NSEG;

    // workspace layout (all 16B-aligned chunks)
    float4* ubbox = (float4*)d_ws;                       // C*N
    float4* sbbox = ubbox + (size_t)C * N;               // C*N
    float4* upay  = sbbox + (size_t)C * N;               // C*N*2
    float4* spay  = upay + (size_t)C * N * 2;            // C*N*2
    float4* partial = spay + (size_t)C * N * 2;          // C*nseg*PIX
    float*  tzbuf = (float*)(partial + (size_t)C * nseg * pix);  // C*N
    int*    tcount = (int*)(tzbuf + (size_t)C * N);      // C*T
    int*    tlist  = tcount + (size_t)C * T;             // C*T*N

    int total = C * N;
    gs_preprocess<<<(total + 255) / 256, 256, 0, stream>>>(
        viewmats, Ks, means, quats, log_scales, opac_logits, color_logits,
        ubbox, upay, tzbuf, N, C);

    gs_sort_wave<<<(total * 64 + 255) / 256, 256, 0, stream>>>(
        ubbox, upay, tzbuf, sbbox, spay, N, C);

    gs_tilebuild<<<(C * T * 64 + 255) / 256, 256, 0, stream>>>(
        sbbox, tcount, tlist, N, C, tilesx, tilesy);

    dim3 grid(tilesx, tilesy, C * nseg);
    gs_render_tile<<<grid, 256, 0, stream>>>(
        spay, tcount, tlist, partial, N, W, H, tilesx, nseg);

    int cp = C * W * H;
    gs_combine<<<(cp + 255) / 256, 256, 0, stream>>>(partial, out, W, H, nseg, C);
}